// Round 5
// baseline (1463.590 us; speedup 1.0000x reference)
//
#include <hip/hip_runtime.h>
#include <cmath>

#define NN 200000
#define EE 6400000
#define NBKT 391          // ceil(200000 / 512), bucket = col >> 9
#define GRID_A 512        // blocks in phase-A kernels (MUST match scan width)
#define BLK_A 256

// =============== Phase A: bucket edges by col>>9 (counting sort, LDS atomics only) ===============

__global__ __launch_bounds__(BLK_A) void count_buckets_kernel(const int* __restrict__ col,
                                                              int* __restrict__ blkhist) {
    __shared__ int h[NBKT];
    for (int t = threadIdx.x; t < NBKT; t += BLK_A) h[t] = 0;
    __syncthreads();
    for (int i = blockIdx.x * BLK_A + threadIdx.x; i < EE; i += GRID_A * BLK_A) {
        atomicAdd(&h[col[i] >> 9], 1);
    }
    __syncthreads();
    for (int t = threadIdx.x; t < NBKT; t += BLK_A) blkhist[blockIdx.x * NBKT + t] = h[t];
}

__global__ __launch_bounds__(GRID_A) void scan_cols_kernel(int* __restrict__ blkhist,
                                                           int* __restrict__ btot) {
    __shared__ int sc[GRID_A];
    int bkt = blockIdx.x, t = threadIdx.x;
    int v = blkhist[t * NBKT + bkt];
    sc[t] = v;
    __syncthreads();
    for (int off = 1; off < GRID_A; off <<= 1) {
        int add = (t >= off) ? sc[t - off] : 0;
        __syncthreads();
        sc[t] += add;
        __syncthreads();
    }
    blkhist[t * NBKT + bkt] = sc[t] - v;  // exclusive along blocks
    if (t == GRID_A - 1) btot[bkt] = sc[t];
}

__global__ __launch_bounds__(512) void scan_btot_kernel(const int* __restrict__ btot,
                                                        int* __restrict__ bbase) {
    __shared__ int sc[512];
    int t = threadIdx.x;
    int v = (t < NBKT) ? btot[t] : 0;
    sc[t] = v;
    __syncthreads();
    for (int off = 1; off < 512; off <<= 1) {
        int add = (t >= off) ? sc[t - off] : 0;
        __syncthreads();
        sc[t] += add;
        __syncthreads();
    }
    if (t < NBKT) bbase[t] = sc[t] - v;
    if (t == NBKT - 1) bbase[NBKT] = sc[t];  // total = EE
}

__global__ __launch_bounds__(BLK_A) void place_pairs_kernel(const int* __restrict__ row,
                                                            const int* __restrict__ col,
                                                            const int* __restrict__ blkhist,
                                                            const int* __restrict__ bbase,
                                                            unsigned int* __restrict__ pairs) {
    __shared__ int cur[NBKT];
    for (int t = threadIdx.x; t < NBKT; t += BLK_A)
        cur[t] = bbase[t] + blkhist[blockIdx.x * NBKT + t];
    __syncthreads();
    for (int i = blockIdx.x * BLK_A + threadIdx.x; i < EE; i += GRID_A * BLK_A) {
        int c = col[i];
        int p = atomicAdd(&cur[c >> 9], 1);
        pairs[p] = (unsigned int)row[i] | ((unsigned int)(c & 511) << 18);
    }
}

__global__ __launch_bounds__(512) void bucket_build_kernel(const unsigned int* __restrict__ pairs,
                                                           const int* __restrict__ bbase,
                                                           int* __restrict__ deg,
                                                           int* __restrict__ offs,
                                                           float* __restrict__ dinv,
                                                           int* __restrict__ row_sorted) {
    __shared__ int h[512];
    __shared__ int sc[512];
    int b = blockIdx.x, tid = threadIdx.x;
    int base = bbase[b], end = bbase[b + 1];
    int node0 = b << 9;
    int nloc = NN - node0; if (nloc > 512) nloc = 512;

    h[tid] = 0;
    __syncthreads();
    for (int i = base + tid; i < end; i += 512) atomicAdd(&h[pairs[i] >> 18], 1);
    __syncthreads();

    int v = h[tid];
    sc[tid] = v;
    __syncthreads();
    for (int off = 1; off < 512; off <<= 1) {
        int add = (tid >= off) ? sc[tid - off] : 0;
        __syncthreads();
        sc[tid] += add;
        __syncthreads();
    }
    int excl = sc[tid] - v;

    if (tid < nloc) {
        deg[node0 + tid]  = v;
        offs[node0 + tid] = base + excl;
        dinv[node0 + tid] = rsqrtf((float)(v + 1));  // +1 self loop
    }
    __syncthreads();
    h[tid] = base + excl;  // local cursor
    __syncthreads();
    for (int i = base + tid; i < end; i += 512) {
        unsigned int p = pairs[i];
        int pos = atomicAdd(&h[p >> 18], 1);
        row_sorted[pos] = (int)(p & 0x3FFFFu);
    }
}

// =============== layer-1 matmul: y1 = dinv * (x @ W1), CHUNK-MAJOR [6][N][4] ===============
__global__ void matmul128_y_kernel(const float* __restrict__ x, const float* __restrict__ W,
                                   const float* __restrict__ dinv, float* __restrict__ y, int n) {
    __shared__ float Ws[128 * 24];
    for (int t = threadIdx.x; t < 128 * 24; t += blockDim.x) Ws[t] = W[t];
    __syncthreads();
    int i = blockIdx.x * blockDim.x + threadIdx.x;
    if (i >= n) return;
    float acc[24];
#pragma unroll
    for (int j = 0; j < 24; ++j) acc[j] = 0.f;
    const float4* hr = (const float4*)(x + (size_t)i * 128);
#pragma unroll 8
    for (int k4 = 0; k4 < 32; ++k4) {
        float4 hv = hr[k4];
        const float* wk = &Ws[k4 * 4 * 24];
#pragma unroll
        for (int j = 0; j < 24; ++j) acc[j] += hv.x * wk[j];
#pragma unroll
        for (int j = 0; j < 24; ++j) acc[j] += hv.y * wk[24 + j];
#pragma unroll
        for (int j = 0; j < 24; ++j) acc[j] += hv.z * wk[48 + j];
#pragma unroll
        for (int j = 0; j < 24; ++j) acc[j] += hv.w * wk[72 + j];
    }
    float di = dinv[i];
#pragma unroll
    for (int c = 0; c < 6; ++c) {
        float4 o;
        o.x = di * acc[c * 4 + 0];
        o.y = di * acc[c * 4 + 1];
        o.z = di * acc[c * 4 + 2];
        o.w = di * acc[c * 4 + 3];
        ((float4*)(y + (size_t)c * NN * 4))[i] = o;
    }
}

// =============== chunked gather-max-tanh ===============
// y,h chunk-major [NCHUNK][NN][CW]; slice = NN*CW*4 bytes (3.2 MB for CW=4 -> L2-resident).
// LPN lanes per node, VEC=CW/LPN floats per lane. blockIdx: chunk-major so chunk
// passes execute ~sequentially (L2 residency heuristic only; correctness unaffected).
template<int CW, int LPN, int NCHUNK>
__global__ __launch_bounds__(256) void gather_chunked_kernel(const int* __restrict__ offs,
                                                             const int* __restrict__ deg,
                                                             const int* __restrict__ row_sorted,
                                                             const float* __restrict__ dinv,
                                                             const float* __restrict__ y,
                                                             const float* __restrict__ b,
                                                             float* __restrict__ h) {
    constexpr int VEC = CW / LPN;
    constexpr int NPB = 256 / LPN;
    constexpr int BPC = (NN + NPB - 1) / NPB;
    typedef float vec_t __attribute__((ext_vector_type(VEC)));
    int chunk = blockIdx.x / BPC;
    int nb    = blockIdx.x - chunk * BPC;
    int ln = threadIdx.x / LPN;
    int j  = threadIdx.x - ln * LPN;
    int node = nb * NPB + ln;
    if (node >= NN) return;
    const vec_t* yv = (const vec_t*)(y + (size_t)chunk * NN * CW);
    float dc = dinv[node];
    vec_t m = yv[(size_t)node * LPN + j];   // self-loop seed (y premultiplied by dinv)
    int s = offs[node];
    int e = s + deg[node];
    int k = s;
    for (; k + 1 < e; k += 2) {
        int r0 = row_sorted[k];
        int r1 = row_sorted[k + 1];
        vec_t v0 = yv[(size_t)r0 * LPN + j];
        vec_t v1 = yv[(size_t)r1 * LPN + j];
#pragma unroll
        for (int c = 0; c < VEC; ++c) m[c] = fmaxf(m[c], fmaxf(v0[c], v1[c]));
    }
    if (k < e) {
        vec_t v0 = yv[(size_t)row_sorted[k] * LPN + j];
#pragma unroll
        for (int c = 0; c < VEC; ++c) m[c] = fmaxf(m[c], v0[c]);
    }
    vec_t o;
#pragma unroll
    for (int c = 0; c < VEC; ++c) o[c] = tanhf(dc * m[c] + b[chunk * CW + j * VEC + c]);
    ((vec_t*)(h + (size_t)chunk * NN * CW))[(size_t)node * LPN + j] = o;
}

// =============== per-layer small matmuls (chunk-major in/out), dinv-premultiplied ===============

// h1 [6][N][4] -> y2 = dc*(h1@W2) [3][N][4]
__global__ __launch_bounds__(256) void mm2_kernel(const float* __restrict__ h1,
                                                  const float* __restrict__ W,   // 24x12
                                                  const float* __restrict__ dinv,
                                                  float* __restrict__ y2) {
    __shared__ float Ws[24 * 12];
    for (int t = threadIdx.x; t < 288; t += 256) Ws[t] = W[t];
    __syncthreads();
    int i = blockIdx.x * 256 + threadIdx.x;
    if (i >= NN) return;
    float hv[24];
#pragma unroll
    for (int c = 0; c < 6; ++c) {
        float4 v = ((const float4*)(h1 + (size_t)c * NN * 4))[i];
        hv[c * 4 + 0] = v.x; hv[c * 4 + 1] = v.y; hv[c * 4 + 2] = v.z; hv[c * 4 + 3] = v.w;
    }
    float dc = dinv[i];
    float acc[12];
#pragma unroll
    for (int j = 0; j < 12; ++j) acc[j] = 0.f;
#pragma unroll
    for (int k = 0; k < 24; ++k)
#pragma unroll
        for (int j = 0; j < 12; ++j) acc[j] += hv[k] * Ws[k * 12 + j];
#pragma unroll
    for (int c = 0; c < 3; ++c) {
        float4 o;
        o.x = dc * acc[c * 4 + 0]; o.y = dc * acc[c * 4 + 1];
        o.z = dc * acc[c * 4 + 2]; o.w = dc * acc[c * 4 + 3];
        ((float4*)(y2 + (size_t)c * NN * 4))[i] = o;
    }
}

// h2 [3][N][4] -> y3a [N][4] (cols 0-3), y3b [N][2] (cols 4-5)
__global__ __launch_bounds__(256) void mm3_kernel(const float* __restrict__ h2,
                                                  const float* __restrict__ W,   // 12x6
                                                  const float* __restrict__ dinv,
                                                  float* __restrict__ y3a,
                                                  float* __restrict__ y3b) {
    __shared__ float Ws[12 * 6];
    for (int t = threadIdx.x; t < 72; t += 256) Ws[t] = W[t];
    __syncthreads();
    int i = blockIdx.x * 256 + threadIdx.x;
    if (i >= NN) return;
    float hv[12];
#pragma unroll
    for (int c = 0; c < 3; ++c) {
        float4 v = ((const float4*)(h2 + (size_t)c * NN * 4))[i];
        hv[c * 4 + 0] = v.x; hv[c * 4 + 1] = v.y; hv[c * 4 + 2] = v.z; hv[c * 4 + 3] = v.w;
    }
    float dc = dinv[i];
    float acc[6];
#pragma unroll
    for (int j = 0; j < 6; ++j) acc[j] = 0.f;
#pragma unroll
    for (int k = 0; k < 12; ++k)
#pragma unroll
        for (int j = 0; j < 6; ++j) acc[j] += hv[k] * Ws[k * 6 + j];
    float4 oa; oa.x = dc * acc[0]; oa.y = dc * acc[1]; oa.z = dc * acc[2]; oa.w = dc * acc[3];
    ((float4*)y3a)[i] = oa;
    float2 ob; ob.x = dc * acc[4]; ob.y = dc * acc[5];
    ((float2*)y3b)[i] = ob;
}

// h3a [N][4] + h3b [N][2] -> y4 [N][4] row-major
__global__ __launch_bounds__(256) void mm4_kernel(const float* __restrict__ h3a,
                                                  const float* __restrict__ h3b,
                                                  const float* __restrict__ W,   // 6x4
                                                  const float* __restrict__ dinv,
                                                  float* __restrict__ y4) {
    __shared__ float Ws[24];
    if (threadIdx.x < 24) Ws[threadIdx.x] = W[threadIdx.x];
    __syncthreads();
    int i = blockIdx.x * 256 + threadIdx.x;
    if (i >= NN) return;
    float4 a = ((const float4*)h3a)[i];
    float2 bb = ((const float2*)h3b)[i];
    float hv[6] = {a.x, a.y, a.z, a.w, bb.x, bb.y};
    float dc = dinv[i];
    float acc[4];
#pragma unroll
    for (int j = 0; j < 4; ++j) acc[j] = 0.f;
#pragma unroll
    for (int k = 0; k < 6; ++k)
#pragma unroll
        for (int j = 0; j < 4; ++j) acc[j] += hv[k] * Ws[k * 4 + j];
    float4 o; o.x = dc * acc[0]; o.y = dc * acc[1]; o.z = dc * acc[2]; o.w = dc * acc[3];
    ((float4*)y4)[i] = o;
}

// =============== layer 4 (DOUT=4) gather + W5 fused -> y5 [N][2] ===============
__global__ __launch_bounds__(256) void gather_fused4_kernel(const int* __restrict__ offs,
                                                            const int* __restrict__ deg,
                                                            const int* __restrict__ row_sorted,
                                                            const float* __restrict__ dinv,
                                                            const float* __restrict__ y,
                                                            const float* __restrict__ b,
                                                            const float* __restrict__ Wn,   // 4x2
                                                            float* __restrict__ ynext) {
    int node = blockIdx.x * 256 + threadIdx.x;
    if (node >= NN) return;
    float dc = dinv[node];
    const float4* yv = (const float4*)y;
    float4 m = yv[node];
    int s = offs[node];
    int e = s + deg[node];
    int k = s;
    for (; k + 1 < e; k += 2) {
        float4 v0 = yv[row_sorted[k]];
        float4 v1 = yv[row_sorted[k + 1]];
        m.x = fmaxf(m.x, fmaxf(v0.x, v1.x));
        m.y = fmaxf(m.y, fmaxf(v0.y, v1.y));
        m.z = fmaxf(m.z, fmaxf(v0.z, v1.z));
        m.w = fmaxf(m.w, fmaxf(v0.w, v1.w));
    }
    if (k < e) {
        float4 v0 = yv[row_sorted[k]];
        m.x = fmaxf(m.x, v0.x); m.y = fmaxf(m.y, v0.y);
        m.z = fmaxf(m.z, v0.z); m.w = fmaxf(m.w, v0.w);
    }
    float h0 = tanhf(dc * m.x + b[0]);
    float h1 = tanhf(dc * m.y + b[1]);
    float h2 = tanhf(dc * m.z + b[2]);
    float h3 = tanhf(dc * m.w + b[3]);
    float2 o;
    o.x = dc * (h0 * Wn[0] + h1 * Wn[2] + h2 * Wn[4] + h3 * Wn[6]);
    o.y = dc * (h0 * Wn[1] + h1 * Wn[3] + h2 * Wn[5] + h3 * Wn[7]);
    ((float2*)ynext)[node] = o;
}

// =============== layer 5 (DOUT=2) gather + classifier fused ===============
__global__ __launch_bounds__(256) void gather_final_kernel(const int* __restrict__ offs,
                                                           const int* __restrict__ deg,
                                                           const int* __restrict__ row_sorted,
                                                           const float* __restrict__ dinv,
                                                           const float* __restrict__ y,
                                                           const float* __restrict__ b,
                                                           const float* __restrict__ Wc,  // 2x4
                                                           const float* __restrict__ bc,
                                                           float* __restrict__ out,
                                                           float* __restrict__ hout) {
    int node = blockIdx.x * 256 + threadIdx.x;
    if (node >= NN) return;
    float dc = dinv[node];
    const float2* yv = (const float2*)y;
    float2 m = yv[node];
    int s = offs[node];
    int e = s + deg[node];
    int k = s;
    for (; k + 1 < e; k += 2) {
        float2 v0 = yv[row_sorted[k]];
        float2 v1 = yv[row_sorted[k + 1]];
        m.x = fmaxf(m.x, fmaxf(v0.x, v1.x));
        m.y = fmaxf(m.y, fmaxf(v0.y, v1.y));
    }
    if (k < e) {
        float2 v0 = yv[row_sorted[k]];
        m.x = fmaxf(m.x, v0.x); m.y = fmaxf(m.y, v0.y);
    }
    float h0 = tanhf(dc * m.x + b[0]);
    float h1 = tanhf(dc * m.y + b[1]);
    float2 ho; ho.x = h0; ho.y = h1;
    ((float2*)hout)[node] = ho;
    float4 o;
    o.x = h0 * Wc[0] + h1 * Wc[4] + bc[0];
    o.y = h0 * Wc[1] + h1 * Wc[5] + bc[1];
    o.z = h0 * Wc[2] + h1 * Wc[6] + bc[2];
    o.w = h0 * Wc[3] + h1 * Wc[7] + bc[3];
    ((float4*)out)[node] = o;
}

extern "C" void kernel_launch(void* const* d_in, const int* in_sizes, int n_in,
                              void* d_out, int out_size, void* d_ws, size_t ws_size,
                              hipStream_t stream) {
    const float* x  = (const float*)d_in[0];
    const int*   ei = (const int*)d_in[1];
    const int* row = ei;            // edge_index[0] = source
    const int* col = ei + EE;       // edge_index[1] = target
    const float* W1 = (const float*)d_in[2];  const float* b1 = (const float*)d_in[3];
    const float* W2 = (const float*)d_in[4];  const float* b2 = (const float*)d_in[5];
    const float* W3 = (const float*)d_in[6];  const float* b3 = (const float*)d_in[7];
    const float* W4 = (const float*)d_in[8];  const float* b4 = (const float*)d_in[9];
    const float* W5 = (const float*)d_in[10]; const float* b5 = (const float*)d_in[11];
    const float* Wc = (const float*)d_in[12]; const float* bc = (const float*)d_in[13];
    float* out = (float*)d_out;

    // ---- workspace carve (73,606,912 B total, same as round 4) ----
    // Region A (25.6 MB): pairs -> y1 -> y2 -> y3a/y3b -> y4   (each dead before overwrite)
    // Region B (25.6 MB): row_sorted (alive throughout)
    // Region C (19.2 MB): h1 -> h2 -> h3a/h3b -> y5
    char* ws = (char*)d_ws;
    int*          deg        = (int*)(ws + 0);          //    800,000
    float*        dinv       = (float*)(ws + 800000);   //    800,000
    int*          offs       = (int*)(ws + 1600000);    //    800,000
    int*          bbase      = (int*)(ws + 2400000);    //      2,048
    int*          blkhist    = (int*)(ws + 2402048);    //    802,816
    int*          btot       = (int*)(ws + 3204864);    //      2,048
    char*         regA       = ws + 3206912;            // 25,600,000
    int*          row_sorted = (int*)(ws + 28806912);   // 25,600,000
    char*         regC       = ws + 54406912;           // 19,200,000

    unsigned int* pairs = (unsigned int*)regA;
    float* y1  = (float*)regA;                 // [6][N][4]
    float* y2  = (float*)regA;                 // [3][N][4]
    float* y3a = (float*)regA;                 // [N][4]
    float* y3b = (float*)(regA + 3200000);     // [N][2]
    float* y4  = (float*)regA;                 // [N][4]
    float* h1  = (float*)regC;                 // [6][N][4]
    float* h2  = (float*)regC;                 // [3][N][4]
    float* h3a = (float*)regC;                 // [N][4]
    float* h3b = (float*)(regC + 3200000);     // [N][2]
    float* y5  = (float*)regC;                 // [N][2]

    const int BLK = 256;
    const int gN = (NN + BLK - 1) / BLK;       // 782
    const int BPC2 = (NN + 127) / 128;         // blocks/chunk for LPN=2 (1563)
    const int BPC1 = (NN + 255) / 256;         // blocks/chunk for LPN=1 (782)

    // ---- CSR build: two-level counting sort, LDS atomics only ----
    count_buckets_kernel<<<GRID_A, BLK_A, 0, stream>>>(col, blkhist);
    scan_cols_kernel<<<NBKT, GRID_A, 0, stream>>>(blkhist, btot);
    scan_btot_kernel<<<1, 512, 0, stream>>>(btot, bbase);
    place_pairs_kernel<<<GRID_A, BLK_A, 0, stream>>>(row, col, blkhist, bbase, pairs);
    bucket_build_kernel<<<NBKT, 512, 0, stream>>>(pairs, bbase, deg, offs, dinv, row_sorted);

    // ---- layer 1: y1 = dinv*(x@W1) chunk-major; gather 6 L2-resident slices -> h1 ----
    matmul128_y_kernel<<<gN, BLK, 0, stream>>>(x, W1, dinv, y1, NN);
    gather_chunked_kernel<4, 2, 6><<<6 * BPC2, 256, 0, stream>>>(
        offs, deg, row_sorted, dinv, y1, b1, h1);

    // ---- layer 2: y2 = dc*(h1@W2) [3][N][4]; gather 3 slices -> h2 ----
    mm2_kernel<<<gN, BLK, 0, stream>>>(h1, W2, dinv, y2);
    gather_chunked_kernel<4, 2, 3><<<3 * BPC2, 256, 0, stream>>>(
        offs, deg, row_sorted, dinv, y2, b2, h2);

    // ---- layer 3: y3 = dc*(h2@W3) split [N][4]+[N][2]; gather both slices -> h3 ----
    mm3_kernel<<<gN, BLK, 0, stream>>>(h2, W3, dinv, y3a, y3b);
    gather_chunked_kernel<4, 2, 1><<<BPC2, 256, 0, stream>>>(
        offs, deg, row_sorted, dinv, y3a, b3, h3a);
    gather_chunked_kernel<2, 1, 1><<<BPC1, 256, 0, stream>>>(
        offs, deg, row_sorted, dinv, y3b, b3 + 4, h3b);

    // ---- layer 4: y4 = dc*(h3@W4) [N][4]; gather + W5 fused -> y5 [N][2] ----
    mm4_kernel<<<gN, BLK, 0, stream>>>(h3a, h3b, W4, dinv, y4);
    gather_fused4_kernel<<<gN, BLK, 0, stream>>>(offs, deg, row_sorted, dinv, y4, b4, W5, y5);

    // ---- layer 5: gather + classifier fused -> out [N][4], h [N][2] ----
    gather_final_kernel<<<gN, BLK, 0, stream>>>(offs, deg, row_sorted, dinv, y5, b5, Wc, bc,
                                                out, out + (size_t)NN * 4);
}

// Round 6
// 851.635 us; speedup vs baseline: 1.7186x; 1.7186x over previous
//
#include <hip/hip_runtime.h>
#include <cmath>

#define NN 200000
#define EE 6400000
#define NBKT 391          // ceil(200000 / 512), bucket = col >> 9
#define GRID_A 512        // blocks in phase-A kernels (MUST match scan width)
#define BLK_A 256

// =============== Phase A: bucket edges by col>>9 (counting sort, LDS atomics only) ===============

// A1: per-block LDS histogram of buckets (int4 edge loads: 4 edges/lane/iter)
__global__ __launch_bounds__(BLK_A) void count_buckets_kernel(const int* __restrict__ col,
                                                              int* __restrict__ blkhist) {
    __shared__ int h[NBKT];
    for (int t = threadIdx.x; t < NBKT; t += BLK_A) h[t] = 0;
    __syncthreads();
    const int4* col4 = (const int4*)col;
    for (int i = blockIdx.x * BLK_A + threadIdx.x; i < EE / 4; i += GRID_A * BLK_A) {
        int4 c = col4[i];
        atomicAdd(&h[c.x >> 9], 1);
        atomicAdd(&h[c.y >> 9], 1);
        atomicAdd(&h[c.z >> 9], 1);
        atomicAdd(&h[c.w >> 9], 1);
    }
    __syncthreads();
    for (int t = threadIdx.x; t < NBKT; t += BLK_A) blkhist[blockIdx.x * NBKT + t] = h[t];
}

__global__ __launch_bounds__(GRID_A) void scan_cols_kernel(int* __restrict__ blkhist,
                                                           int* __restrict__ btot) {
    __shared__ int sc[GRID_A];
    int bkt = blockIdx.x, t = threadIdx.x;
    int v = blkhist[t * NBKT + bkt];
    sc[t] = v;
    __syncthreads();
    for (int off = 1; off < GRID_A; off <<= 1) {
        int add = (t >= off) ? sc[t - off] : 0;
        __syncthreads();
        sc[t] += add;
        __syncthreads();
    }
    blkhist[t * NBKT + bkt] = sc[t] - v;  // exclusive along blocks
    if (t == GRID_A - 1) btot[bkt] = sc[t];
}

__global__ __launch_bounds__(512) void scan_btot_kernel(const int* __restrict__ btot,
                                                        int* __restrict__ bbase) {
    __shared__ int sc[512];
    int t = threadIdx.x;
    int v = (t < NBKT) ? btot[t] : 0;
    sc[t] = v;
    __syncthreads();
    for (int off = 1; off < 512; off <<= 1) {
        int add = (t >= off) ? sc[t - off] : 0;
        __syncthreads();
        sc[t] += add;
        __syncthreads();
    }
    if (t < NBKT) bbase[t] = sc[t] - v;
    if (t == NBKT - 1) bbase[NBKT] = sc[t];  // total = EE
}

// A3: place packed codes (int4 edge loads). code = (col&511)<<18 | row  (row < 2^18)
__global__ __launch_bounds__(BLK_A) void place_pairs_kernel(const int* __restrict__ row,
                                                            const int* __restrict__ col,
                                                            const int* __restrict__ blkhist,
                                                            const int* __restrict__ bbase,
                                                            unsigned int* __restrict__ pairs) {
    __shared__ int cur[NBKT];
    for (int t = threadIdx.x; t < NBKT; t += BLK_A)
        cur[t] = bbase[t] + blkhist[blockIdx.x * NBKT + t];
    __syncthreads();
    const int4* col4 = (const int4*)col;
    const int4* row4 = (const int4*)row;
    for (int i = blockIdx.x * BLK_A + threadIdx.x; i < EE / 4; i += GRID_A * BLK_A) {
        int4 c = col4[i];
        int4 r = row4[i];
        int p0 = atomicAdd(&cur[c.x >> 9], 1);
        pairs[p0] = (unsigned int)r.x | ((unsigned int)(c.x & 511) << 18);
        int p1 = atomicAdd(&cur[c.y >> 9], 1);
        pairs[p1] = (unsigned int)r.y | ((unsigned int)(c.y & 511) << 18);
        int p2 = atomicAdd(&cur[c.z >> 9], 1);
        pairs[p2] = (unsigned int)r.z | ((unsigned int)(c.z & 511) << 18);
        int p3 = atomicAdd(&cur[c.w >> 9], 1);
        pairs[p3] = (unsigned int)r.w | ((unsigned int)(c.w & 511) << 18);
    }
}

__global__ __launch_bounds__(512) void bucket_build_kernel(const unsigned int* __restrict__ pairs,
                                                           const int* __restrict__ bbase,
                                                           int* __restrict__ deg,
                                                           int* __restrict__ offs,
                                                           float* __restrict__ dinv,
                                                           int* __restrict__ row_sorted) {
    __shared__ int h[512];
    __shared__ int sc[512];
    int b = blockIdx.x, tid = threadIdx.x;
    int base = bbase[b], end = bbase[b + 1];
    int node0 = b << 9;
    int nloc = NN - node0; if (nloc > 512) nloc = 512;

    h[tid] = 0;
    __syncthreads();
    for (int i = base + tid; i < end; i += 512) atomicAdd(&h[pairs[i] >> 18], 1);
    __syncthreads();

    int v = h[tid];
    sc[tid] = v;
    __syncthreads();
    for (int off = 1; off < 512; off <<= 1) {
        int add = (tid >= off) ? sc[tid - off] : 0;
        __syncthreads();
        sc[tid] += add;
        __syncthreads();
    }
    int excl = sc[tid] - v;

    if (tid < nloc) {
        deg[node0 + tid]  = v;
        offs[node0 + tid] = base + excl;
        dinv[node0 + tid] = rsqrtf((float)(v + 1));  // +1 self loop
    }
    __syncthreads();
    h[tid] = base + excl;  // local cursor
    __syncthreads();
    for (int i = base + tid; i < end; i += 512) {
        unsigned int p = pairs[i];
        int pos = atomicAdd(&h[p >> 18], 1);
        row_sorted[pos] = (int)(p & 0x3FFFFu);
    }
}

// =============== layer-1 matmul, epilogue premultiplies dinv: y = dinv[i] * (x[i] @ W) ===============
__global__ void matmul128_y_kernel(const float* __restrict__ x, const float* __restrict__ W,
                                   const float* __restrict__ dinv, float* __restrict__ y, int n) {
    __shared__ float Ws[128 * 24];
    for (int t = threadIdx.x; t < 128 * 24; t += blockDim.x) Ws[t] = W[t];
    __syncthreads();
    int i = blockIdx.x * blockDim.x + threadIdx.x;
    if (i >= n) return;
    float acc[24];
#pragma unroll
    for (int j = 0; j < 24; ++j) acc[j] = 0.f;
    const float4* hr = (const float4*)(x + (size_t)i * 128);
#pragma unroll 8
    for (int k4 = 0; k4 < 32; ++k4) {
        float4 hv = hr[k4];
        const float* wk = &Ws[k4 * 4 * 24];
#pragma unroll
        for (int j = 0; j < 24; ++j) acc[j] += hv.x * wk[j];
#pragma unroll
        for (int j = 0; j < 24; ++j) acc[j] += hv.y * wk[24 + j];
#pragma unroll
        for (int j = 0; j < 24; ++j) acc[j] += hv.z * wk[48 + j];
#pragma unroll
        for (int j = 0; j < 24; ++j) acc[j] += hv.w * wk[72 + j];
    }
    float di = dinv[i];
    float4* orow = (float4*)(y + (size_t)i * 24);
#pragma unroll
    for (int q = 0; q < 6; ++q) {
        float4 o;
        o.x = di * acc[q * 4 + 0];
        o.y = di * acc[q * 4 + 1];
        o.z = di * acc[q * 4 + 2];
        o.w = di * acc[q * 4 + 3];
        orow[q] = o;
    }
}

// =============== fused gather-max-tanh + next matmul (LDS h staging), 4x unrolled ===============
template<int DOUT, int DNEXT, int VEC>
__global__ __launch_bounds__(256) void gather_fused_kernel(const int* __restrict__ offs,
                                                           const int* __restrict__ deg,
                                                           const int* __restrict__ row_sorted,
                                                           const float* __restrict__ dinv,
                                                           const float* __restrict__ y,
                                                           const float* __restrict__ b,
                                                           const float* __restrict__ Wn,
                                                           float* __restrict__ ynext) {
    constexpr int LPN = DOUT / VEC;        // lanes per node
    constexpr int NPB = 256 / LPN;         // nodes per block
    typedef float vec_t __attribute__((ext_vector_type(VEC)));

    __shared__ float hs[NPB * DOUT];
    __shared__ float dcs[NPB];

    int ln = threadIdx.x / LPN;
    int j  = threadIdx.x % LPN;
    int node = blockIdx.x * NPB + ln;
    bool active = (ln < NPB) && (node < NN);

    if (active) {
        float dc = dinv[node];
        const vec_t* yv = (const vec_t*)y;
        vec_t m = yv[(size_t)node * LPN + j];   // self-loop seed (y already has dinv_self)
        int s = offs[node];
        int e = s + deg[node];
        int k = s;
        for (; k + 3 < e; k += 4) {            // 4 independent loads in flight (MLP)
            int r0 = row_sorted[k];
            int r1 = row_sorted[k + 1];
            int r2 = row_sorted[k + 2];
            int r3 = row_sorted[k + 3];
            vec_t v0 = yv[(size_t)r0 * LPN + j];
            vec_t v1 = yv[(size_t)r1 * LPN + j];
            vec_t v2 = yv[(size_t)r2 * LPN + j];
            vec_t v3 = yv[(size_t)r3 * LPN + j];
#pragma unroll
            for (int c = 0; c < VEC; ++c)
                m[c] = fmaxf(m[c], fmaxf(fmaxf(v0[c], v1[c]), fmaxf(v2[c], v3[c])));
        }
        for (; k < e; ++k) {
            vec_t v0 = yv[(size_t)row_sorted[k] * LPN + j];
#pragma unroll
            for (int c = 0; c < VEC; ++c) m[c] = fmaxf(m[c], v0[c]);
        }
#pragma unroll
        for (int c = 0; c < VEC; ++c)
            hs[ln * DOUT + j * VEC + c] = tanhf(dc * m[c] + b[j * VEC + c]);
        if (j == 0) dcs[ln] = dc;
    }
    __syncthreads();

    // phase 2: y_next = dc * (h @ Wn) for the staged nodes
    for (int idx = threadIdx.x; idx < NPB * DNEXT; idx += 256) {
        int ln2 = idx / DNEXT;
        int j2 = idx - ln2 * DNEXT;
        int gn = blockIdx.x * NPB + ln2;
        if (gn < NN) {
            float acc = 0.f;
#pragma unroll
            for (int k = 0; k < DOUT; ++k) acc += hs[ln2 * DOUT + k] * Wn[k * DNEXT + j2];
            ynext[(size_t)gn * DNEXT + j2] = dcs[ln2] * acc;
        }
    }
}

// =============== layer 4 (DOUT=4): whole row in one thread, no LDS, 4x unrolled ===============
__global__ __launch_bounds__(256) void gather_fused4_kernel(const int* __restrict__ offs,
                                                            const int* __restrict__ deg,
                                                            const int* __restrict__ row_sorted,
                                                            const float* __restrict__ dinv,
                                                            const float* __restrict__ y,
                                                            const float* __restrict__ b,
                                                            const float* __restrict__ Wn,   // 4x2
                                                            float* __restrict__ ynext) {
    int node = blockIdx.x * 256 + threadIdx.x;
    if (node >= NN) return;
    float dc = dinv[node];
    const float4* yv = (const float4*)y;
    float4 m = yv[node];
    int s = offs[node];
    int e = s + deg[node];
    int k = s;
    for (; k + 3 < e; k += 4) {
        float4 v0 = yv[row_sorted[k]];
        float4 v1 = yv[row_sorted[k + 1]];
        float4 v2 = yv[row_sorted[k + 2]];
        float4 v3 = yv[row_sorted[k + 3]];
        m.x = fmaxf(m.x, fmaxf(fmaxf(v0.x, v1.x), fmaxf(v2.x, v3.x)));
        m.y = fmaxf(m.y, fmaxf(fmaxf(v0.y, v1.y), fmaxf(v2.y, v3.y)));
        m.z = fmaxf(m.z, fmaxf(fmaxf(v0.z, v1.z), fmaxf(v2.z, v3.z)));
        m.w = fmaxf(m.w, fmaxf(fmaxf(v0.w, v1.w), fmaxf(v2.w, v3.w)));
    }
    for (; k < e; ++k) {
        float4 v0 = yv[row_sorted[k]];
        m.x = fmaxf(m.x, v0.x); m.y = fmaxf(m.y, v0.y);
        m.z = fmaxf(m.z, v0.z); m.w = fmaxf(m.w, v0.w);
    }
    float h0 = tanhf(dc * m.x + b[0]);
    float h1 = tanhf(dc * m.y + b[1]);
    float h2 = tanhf(dc * m.z + b[2]);
    float h3 = tanhf(dc * m.w + b[3]);
    float2 o;
    o.x = dc * (h0 * Wn[0] + h1 * Wn[2] + h2 * Wn[4] + h3 * Wn[6]);
    o.y = dc * (h0 * Wn[1] + h1 * Wn[3] + h2 * Wn[5] + h3 * Wn[7]);
    ((float2*)ynext)[node] = o;
}

// =============== layer 5 (DOUT=2) + classifier, no LDS, 4x unrolled ===============
__global__ __launch_bounds__(256) void gather_final_kernel(const int* __restrict__ offs,
                                                           const int* __restrict__ deg,
                                                           const int* __restrict__ row_sorted,
                                                           const float* __restrict__ dinv,
                                                           const float* __restrict__ y,
                                                           const float* __restrict__ b,
                                                           const float* __restrict__ Wc,  // 2x4
                                                           const float* __restrict__ bc,
                                                           float* __restrict__ out,
                                                           float* __restrict__ hout) {
    int node = blockIdx.x * 256 + threadIdx.x;
    if (node >= NN) return;
    float dc = dinv[node];
    const float2* yv = (const float2*)y;
    float2 m = yv[node];
    int s = offs[node];
    int e = s + deg[node];
    int k = s;
    for (; k + 3 < e; k += 4) {
        float2 v0 = yv[row_sorted[k]];
        float2 v1 = yv[row_sorted[k + 1]];
        float2 v2 = yv[row_sorted[k + 2]];
        float2 v3 = yv[row_sorted[k + 3]];
        m.x = fmaxf(m.x, fmaxf(fmaxf(v0.x, v1.x), fmaxf(v2.x, v3.x)));
        m.y = fmaxf(m.y, fmaxf(fmaxf(v0.y, v1.y), fmaxf(v2.y, v3.y)));
    }
    for (; k < e; ++k) {
        float2 v0 = yv[row_sorted[k]];
        m.x = fmaxf(m.x, v0.x); m.y = fmaxf(m.y, v0.y);
    }
    float h0 = tanhf(dc * m.x + b[0]);
    float h1 = tanhf(dc * m.y + b[1]);
    float2 ho; ho.x = h0; ho.y = h1;
    ((float2*)hout)[node] = ho;
    float4 o;
    o.x = h0 * Wc[0] + h1 * Wc[4] + bc[0];
    o.y = h0 * Wc[1] + h1 * Wc[5] + bc[1];
    o.z = h0 * Wc[2] + h1 * Wc[6] + bc[2];
    o.w = h0 * Wc[3] + h1 * Wc[7] + bc[3];
    ((float4*)out)[node] = o;
}

extern "C" void kernel_launch(void* const* d_in, const int* in_sizes, int n_in,
                              void* d_out, int out_size, void* d_ws, size_t ws_size,
                              hipStream_t stream) {
    const float* x  = (const float*)d_in[0];
    const int*   ei = (const int*)d_in[1];
    const int* row = ei;            // edge_index[0] = source
    const int* col = ei + EE;       // edge_index[1] = target
    const float* W1 = (const float*)d_in[2];  const float* b1 = (const float*)d_in[3];
    const float* W2 = (const float*)d_in[4];  const float* b2 = (const float*)d_in[5];
    const float* W3 = (const float*)d_in[6];  const float* b3 = (const float*)d_in[7];
    const float* W4 = (const float*)d_in[8];  const float* b4 = (const float*)d_in[9];
    const float* W5 = (const float*)d_in[10]; const float* b5 = (const float*)d_in[11];
    const float* Wc = (const float*)d_in[12]; const float* bc = (const float*)d_in[13];
    float* out = (float*)d_out;

    // ---- workspace carve ----
    // pairs (25.6 MB) is dead before matmul128_y writes bufB -> alias them.
    char* ws = (char*)d_ws;
    int*          deg        = (int*)(ws + 0);          //    800,000
    float*        dinv       = (float*)(ws + 800000);   //    800,000
    int*          offs       = (int*)(ws + 1600000);    //    800,000
    int*          bbase      = (int*)(ws + 2400000);    //      2,048  (NBKT+1 ints)
    int*          blkhist    = (int*)(ws + 2402048);    //    802,816  (GRID_A*NBKT ints)
    int*          btot       = (int*)(ws + 3204864);    //      2,048
    unsigned int* pairs      = (unsigned int*)(ws + 3206912);   // 25,600,000
    float*        bufB       = (float*)(ws + 3206912);          // 25,600,000 (aliases pairs; y1/y3/y5)
    int*          row_sorted = (int*)(ws + 28806912);           // 25,600,000
    float*        bufA       = (float*)(ws + 54406912);         // 19,200,000 (y2/y4)
    // total: 73,606,912 B

    const int BLK = 256;
    const int gN = (NN + BLK - 1) / BLK;       // 782

    // ---- CSR build: two-level counting sort, LDS atomics only ----
    count_buckets_kernel<<<GRID_A, BLK_A, 0, stream>>>(col, blkhist);
    scan_cols_kernel<<<NBKT, GRID_A, 0, stream>>>(blkhist, btot);
    scan_btot_kernel<<<1, 512, 0, stream>>>(btot, bbase);
    place_pairs_kernel<<<GRID_A, BLK_A, 0, stream>>>(row, col, blkhist, bbase, pairs);
    bucket_build_kernel<<<NBKT, 512, 0, stream>>>(pairs, bbase, deg, offs, dinv, row_sorted);

    // ---- layer 1 matmul: y1 = dinv * (x @ W1), [N,24] ----
    matmul128_y_kernel<<<gN, BLK, 0, stream>>>(x, W1, dinv, bufB, NN);

    // ---- layer 1 gather + layer-2 matmul fused: y2 [N,12] ----
    {
        constexpr int NPB = 256 / (24 / 4);   // 42 nodes/block
        gather_fused_kernel<24, 12, 4><<<(NN + NPB - 1) / NPB, 256, 0, stream>>>(
            offs, deg, row_sorted, dinv, bufB, b1, W2, bufA);
    }
    // ---- layer 2 gather + layer-3 matmul fused: y3 [N,6] ----
    {
        constexpr int NPB = 256 / (12 / 4);   // 85 nodes/block
        gather_fused_kernel<12, 6, 4><<<(NN + NPB - 1) / NPB, 256, 0, stream>>>(
            offs, deg, row_sorted, dinv, bufA, b2, W3, bufB);
    }
    // ---- layer 3 gather + layer-4 matmul fused: y4 [N,4] ----
    {
        constexpr int NPB = 256 / (6 / 2);    // 85 nodes/block
        gather_fused_kernel<6, 4, 2><<<(NN + NPB - 1) / NPB, 256, 0, stream>>>(
            offs, deg, row_sorted, dinv, bufB, b3, W4, bufA);
    }
    // ---- layer 4 gather + layer-5 matmul fused: y5 [N,2] ----
    gather_fused4_kernel<<<gN, BLK, 0, stream>>>(offs, deg, row_sorted, dinv, bufA, b4, W5, bufB);

    // ---- layer 5 gather + classifier fused: out [N,4], h [N,2] ----
    gather_final_kernel<<<gN, BLK, 0, stream>>>(offs, deg, row_sorted, dinv, bufB, b5, Wc, bc,
                                                out, out + (size_t)NN * 4);
}